// Round 2
// baseline (234.440 us; speedup 1.0000x reference)
//
#include <hip/hip_runtime.h>

// Tiny ViT forward, B=8192, fp32 end-to-end (device buffers are fp32).
// One lane per (image, token); 5 images per 256-thread block (250 active
// lanes). All weights staged to LDS once. K/V exchanged via LDS per
// transformer block; two-pass softmax per head.

#define T_TOK   50
#define IMGS_PB 5
#define THREADS 256
#define SCALE   0.35355339059327373f   // 8^-0.5

// LDS float offsets
#define OFF_LIN 0       // 128   lin_W [8][16]
#define OFF_WQ  128     // 256   Wq [4][8][8]
#define OFF_WK  384     // 256
#define OFF_WV  640     // 256
#define OFF_PW  896     // 256   proj_W [4][8][8]
#define OFF_PB  1152    // 32
#define OFF_G1  1184    // 32
#define OFF_B1  1216    // 32
#define OFF_G2  1248    // 32
#define OFF_B2  1280    // 32
#define OFF_W1  1312    // 1024  W1 [4][32][8]
#define OFF_BB1 2336    // 128
#define OFF_W2  2464    // 1024  W2 [4][8][32]
#define OFF_BB2 3488    // 32
#define OFF_KV  3520    // 5*50*16
#define LDS_FLOATS (OFF_KV + IMGS_PB * T_TOK * 16)

__global__ __launch_bounds__(THREADS) void vit_fwd(
    const float* __restrict__ images, const float* __restrict__ cls,
    const float* __restrict__ linW,
    const float* __restrict__ g1,  const float* __restrict__ be1,
    const float* __restrict__ Wq,  const float* __restrict__ Wk,
    const float* __restrict__ Wv,  const float* __restrict__ Pw,
    const float* __restrict__ Pb,  const float* __restrict__ g2,
    const float* __restrict__ be2, const float* __restrict__ W1,
    const float* __restrict__ bb1, const float* __restrict__ W2,
    const float* __restrict__ bb2, const float* __restrict__ mlpW,
    const float* __restrict__ mlpb,
    float* __restrict__ out, int B)
{
    __shared__ float lds[LDS_FLOATS];
    const int tid = threadIdx.x;

    {   // stage all weights to LDS
        auto stage = [&](int off, const float* src, int n) {
            for (int i = tid; i < n; i += THREADS) lds[off + i] = src[i];
        };
        stage(OFF_LIN, linW, 128);
        stage(OFF_WQ, Wq, 256);  stage(OFF_WK, Wk, 256);  stage(OFF_WV, Wv, 256);
        stage(OFF_PW, Pw, 256);  stage(OFF_PB, Pb, 32);
        stage(OFF_G1, g1, 32);   stage(OFF_B1, be1, 32);
        stage(OFF_G2, g2, 32);   stage(OFF_B2, be2, 32);
        stage(OFF_W1, W1, 1024); stage(OFF_BB1, bb1, 128);
        stage(OFF_W2, W2, 1024); stage(OFF_BB2, bb2, 32);
    }
    __syncthreads();

    const int imgl = tid / T_TOK;          // 0..4 (5 for tid>=250, unused)
    const int t    = tid - imgl * T_TOK;   // token index 0..49
    const int gimg = blockIdx.x * IMGS_PB + imgl;
    const bool active = (tid < IMGS_PB * T_TOK) && (gimg < B);

    float x[8];
    if (active) {
        // sinusoidal positional embedding; 10000^(e/8) for e in {0,2,4,6}
        // is exactly {1,10,100,1000}
        float pos[8];
        const float FR[4] = {1.f, 0.1f, 0.01f, 0.001f};
        #pragma unroll
        for (int j = 0; j < 8; ++j) {
            float arg = (float)t * FR[j >> 1];
            pos[j] = (j & 1) ? __cosf(arg) : __sinf(arg);
        }
        if (t == 0) {
            #pragma unroll
            for (int e = 0; e < 8; ++e) x[e] = cls[e] + pos[e];
        } else {
            const int p = t - 1, pr = p / 7, pc = p - pr * 7;
            const float* ib = images + (size_t)gimg * 784 + pr * 112 + pc * 4;
            float pf[16];
            #pragma unroll
            for (int r = 0; r < 4; ++r) {      // 16B-aligned float4 loads
                float4 u = *reinterpret_cast<const float4*>(ib + r * 28);
                pf[r*4+0] = u.x; pf[r*4+1] = u.y;
                pf[r*4+2] = u.z; pf[r*4+3] = u.w;
            }
            #pragma unroll
            for (int e = 0; e < 8; ++e) {
                float a = 0.f;
                #pragma unroll
                for (int i = 0; i < 16; ++i) a += pf[i] * lds[OFF_LIN + e*16 + i];
                x[e] = a + pos[e];
            }
        }
    }

    for (int blk = 0; blk < 4; ++blk) {
        float q[8], kk[8], vv[8];
        if (active) {
            // LN1
            float mu = 0.f;
            #pragma unroll
            for (int d = 0; d < 8; ++d) mu += x[d];
            mu *= 0.125f;
            float var = 0.f;
            #pragma unroll
            for (int d = 0; d < 8; ++d) { float dd = x[d] - mu; var += dd * dd; }
            var *= 0.125f;
            const float rs = rsqrtf(var + 1e-5f);
            float h[8];
            #pragma unroll
            for (int d = 0; d < 8; ++d)
                h[d] = (x[d] - mu) * rs * lds[OFF_G1 + blk*8 + d] + lds[OFF_B1 + blk*8 + d];
            // q,k,v projections ([out][in] weights)
            const float* wq = lds + OFF_WQ + blk * 64;
            const float* wk = lds + OFF_WK + blk * 64;
            const float* wv = lds + OFF_WV + blk * 64;
            #pragma unroll
            for (int e = 0; e < 8; ++e) {
                float aq = 0.f, ak = 0.f, av = 0.f;
                #pragma unroll
                for (int d = 0; d < 8; ++d) {
                    aq += h[d] * wq[e*8+d];
                    ak += h[d] * wk[e*8+d];
                    av += h[d] * wv[e*8+d];
                }
                q[e] = aq * SCALE; kk[e] = ak; vv[e] = av;
            }
        }
        __syncthreads();   // prev-iter attention reads of kv done
        if (active) {
            float* kvp = lds + OFF_KV + (imgl * T_TOK + t) * 16;
            *reinterpret_cast<float4*>(kvp +  0) = make_float4(kk[0],kk[1],kk[2],kk[3]);
            *reinterpret_cast<float4*>(kvp +  4) = make_float4(kk[4],kk[5],kk[6],kk[7]);
            *reinterpret_cast<float4*>(kvp +  8) = make_float4(vv[0],vv[1],vv[2],vv[3]);
            *reinterpret_cast<float4*>(kvp + 12) = make_float4(vv[4],vv[5],vv[6],vv[7]);
        }
        __syncthreads();
        if (active) {
            const float* kvb = lds + OFF_KV + imgl * T_TOK * 16;
            float o[8];
            #pragma unroll
            for (int hh = 0; hh < 2; ++hh) {
                const float q0 = q[hh*4+0], q1 = q[hh*4+1];
                const float q2 = q[hh*4+2], q3 = q[hh*4+3];
                float m = -1e30f;
                for (int s = 0; s < T_TOK; ++s) {
                    float4 k4 = *reinterpret_cast<const float4*>(kvb + s*16 + hh*4);
                    float d = q0*k4.x + q1*k4.y + q2*k4.z + q3*k4.w;
                    m = fmaxf(m, d);
                }
                float l = 0.f, a0 = 0.f, a1 = 0.f, a2 = 0.f, a3 = 0.f;
                for (int s = 0; s < T_TOK; ++s) {
                    float4 k4 = *reinterpret_cast<const float4*>(kvb + s*16 + hh*4);
                    float d = q0*k4.x + q1*k4.y + q2*k4.z + q3*k4.w;
                    float p = __expf(d - m);
                    float4 v4 = *reinterpret_cast<const float4*>(kvb + s*16 + 8 + hh*4);
                    l += p;
                    a0 += p*v4.x; a1 += p*v4.y; a2 += p*v4.z; a3 += p*v4.w;
                }
                const float rl = 1.f / l;
                o[hh*4+0] = a0*rl; o[hh*4+1] = a1*rl;
                o[hh*4+2] = a2*rl; o[hh*4+3] = a3*rl;
            }
            // proj + residual
            const float* pw = lds + OFF_PW + blk * 64;
            float xn[8];
            #pragma unroll
            for (int e = 0; e < 8; ++e) {
                float a = lds[OFF_PB + blk*8 + e];
                #pragma unroll
                for (int d = 0; d < 8; ++d) a += o[d] * pw[e*8+d];
                xn[e] = x[e] + a;
            }
            #pragma unroll
            for (int e = 0; e < 8; ++e) x[e] = xn[e];
            // LN2
            float mu = 0.f;
            #pragma unroll
            for (int d = 0; d < 8; ++d) mu += x[d];
            mu *= 0.125f;
            float var = 0.f;
            #pragma unroll
            for (int d = 0; d < 8; ++d) { float dd = x[d] - mu; var += dd * dd; }
            var *= 0.125f;
            const float rs2 = rsqrtf(var + 1e-5f);
            float h2[8];
            #pragma unroll
            for (int d = 0; d < 8; ++d)
                h2[d] = (x[d] - mu) * rs2 * lds[OFF_G2 + blk*8 + d] + lds[OFF_B2 + blk*8 + d];
            // FF: stream over f, no 32-wide array
            float acc[8] = {0.f,0.f,0.f,0.f,0.f,0.f,0.f,0.f};
            const float* w1 = lds + OFF_W1 + blk * 256;
            const float* w2 = lds + OFF_W2 + blk * 256;
            #pragma unroll 4
            for (int f = 0; f < 32; ++f) {
                float a = lds[OFF_BB1 + blk*32 + f];
                #pragma unroll
                for (int d = 0; d < 8; ++d) a += h2[d] * w1[f*8+d];
                a = fmaxf(a, 0.f);
                #pragma unroll
                for (int d = 0; d < 8; ++d) acc[d] += a * w2[d*32+f];
            }
            #pragma unroll
            for (int d = 0; d < 8; ++d) x[d] += acc[d] + lds[OFF_BB2 + blk*8 + d];
        }
    }

    // classification head: only cls-token lanes
    if (active && t == 0) {
        float lg[10]; float mx = -1e30f;
        #pragma unroll
        for (int c = 0; c < 10; ++c) {
            float a = mlpb[c];
            #pragma unroll
            for (int d = 0; d < 8; ++d) a += x[d] * mlpW[c*8+d];
            lg[c] = a; mx = fmaxf(mx, a);
        }
        float ssum = 0.f;
        #pragma unroll
        for (int c = 0; c < 10; ++c) { lg[c] = __expf(lg[c] - mx); ssum += lg[c]; }
        const float rsum = 1.f / ssum;
        #pragma unroll
        for (int c = 0; c < 10; ++c)
            out[(size_t)gimg*10 + c] = lg[c] * rsum;
    }
}

extern "C" void kernel_launch(void* const* d_in, const int* in_sizes, int n_in,
                              void* d_out, int out_size, void* d_ws, size_t ws_size,
                              hipStream_t stream) {
    const int B = in_sizes[0] / 784;
    const int nblk = (B + IMGS_PB - 1) / IMGS_PB;
    vit_fwd<<<nblk, THREADS, 0, stream>>>(
        (const float*)d_in[0],  (const float*)d_in[1],  (const float*)d_in[2],
        (const float*)d_in[3],  (const float*)d_in[4],  (const float*)d_in[5],
        (const float*)d_in[6],  (const float*)d_in[7],  (const float*)d_in[8],
        (const float*)d_in[9],  (const float*)d_in[10], (const float*)d_in[11],
        (const float*)d_in[12], (const float*)d_in[13], (const float*)d_in[14],
        (const float*)d_in[15], (const float*)d_in[16], (const float*)d_in[17],
        (float*)d_out, B);
}

// Round 3
// 142.365 us; speedup vs baseline: 1.6468x; 1.6468x over previous
//
#include <hip/hip_runtime.h>

// Tiny ViT forward, B=8192, fp32. One lane per (image, token-PAIR):
// 25 lanes/image, 10 images per 256-thread block (250 active lanes).
// Weights are read directly from global with wave-uniform indices ->
// compiler emits s_load (SMEM pipe, SGPR operands) -> near-zero LDS
// traffic for weights. LDS holds only K/V (padded stride). Softmax is
// one-pass with no max subtraction (scores are ~0.06 std; exp-safe).

#define T_TOK   50
#define TPI     25          // token-pairs (lanes) per image
#define IMGS_PB 10
#define THREADS 256
#define KV_STRIDE 808       // 50*16 + 8 pad (breaks %32 bank aliasing)
#define SCALE   0.35355339059327373f   // 8^-0.5

__global__ __launch_bounds__(THREADS) void vit_fwd(
    const float* __restrict__ images, const float* __restrict__ cls,
    const float* __restrict__ linW,
    const float* __restrict__ g1,  const float* __restrict__ be1,
    const float* __restrict__ Wq,  const float* __restrict__ Wk,
    const float* __restrict__ Wv,  const float* __restrict__ Pw,
    const float* __restrict__ Pb,  const float* __restrict__ g2,
    const float* __restrict__ be2, const float* __restrict__ W1,
    const float* __restrict__ bb1, const float* __restrict__ W2,
    const float* __restrict__ bb2, const float* __restrict__ mlpW,
    const float* __restrict__ mlpb,
    float* __restrict__ out, int B)
{
    __shared__ float kv[IMGS_PB * KV_STRIDE];   // 32320 B

    const int tid  = threadIdx.x;
    const int imgl = tid / TPI;            // 0..9
    const int lt   = tid - imgl * TPI;     // 0..24
    const int t0   = lt * 2;               // tokens t0, t0+1
    const int gimg = blockIdx.x * IMGS_PB + imgl;
    const bool active = (tid < TPI * IMGS_PB) && (gimg < B);

    // ---- patch embed + positional ----
    auto embed = [&](int t, float* xo) {
        const float FR[4] = {1.f, 0.1f, 0.01f, 0.001f};
        float pos[8];
        #pragma unroll
        for (int j = 0; j < 8; ++j) {
            float arg = (float)t * FR[j >> 1];
            pos[j] = (j & 1) ? __cosf(arg) : __sinf(arg);
        }
        if (t == 0) {
            #pragma unroll
            for (int e = 0; e < 8; ++e) xo[e] = cls[e] + pos[e];
        } else {
            const int p = t - 1, pr = p / 7, pc = p - pr * 7;
            const float* ib = images + (size_t)gimg * 784 + pr * 112 + pc * 4;
            float pf[16];
            #pragma unroll
            for (int r = 0; r < 4; ++r) {
                float4 u = *reinterpret_cast<const float4*>(ib + r * 28);
                pf[r*4+0] = u.x; pf[r*4+1] = u.y;
                pf[r*4+2] = u.z; pf[r*4+3] = u.w;
            }
            #pragma unroll
            for (int e = 0; e < 8; ++e) {
                float a = 0.f;
                #pragma unroll
                for (int i = 0; i < 16; ++i) a += pf[i] * linW[e*16 + i];
                xo[e] = a + pos[e];
            }
        }
    };

    float x0[8], x1[8];
    if (active) { embed(t0, x0); embed(t0 + 1, x1); }

    for (int blk = 0; blk < 4; ++blk) {
        const int w8  = blk * 8;
        const int w64 = blk * 64;
        const int w256 = blk * 256;
        const int w32 = blk * 32;

        __syncthreads();   // previous iteration's K/V reads complete

        // ---- LN1 + qkv; write K/V to LDS; keep q in regs ----
        float q0[8], q1[8];
        auto qkv = [&](const float* xi, int t, float* qo) {
            float mu = 0.f;
            #pragma unroll
            for (int d = 0; d < 8; ++d) mu += xi[d];
            mu *= 0.125f;
            float var = 0.f;
            #pragma unroll
            for (int d = 0; d < 8; ++d) { float dd = xi[d] - mu; var += dd * dd; }
            var *= 0.125f;
            const float rs = rsqrtf(var + 1e-5f);
            float h[8];
            #pragma unroll
            for (int d = 0; d < 8; ++d)
                h[d] = (xi[d] - mu) * rs * g1[w8 + d] + be1[w8 + d];
            float kk[8], vv[8];
            #pragma unroll
            for (int e = 0; e < 8; ++e) {
                float aq = 0.f, ak = 0.f, av = 0.f;
                #pragma unroll
                for (int d = 0; d < 8; ++d) {
                    aq += h[d] * Wq[w64 + e*8 + d];
                    ak += h[d] * Wk[w64 + e*8 + d];
                    av += h[d] * Wv[w64 + e*8 + d];
                }
                qo[e] = aq * SCALE; kk[e] = ak; vv[e] = av;
            }
            float* kvp = kv + imgl * KV_STRIDE + t * 16;
            *reinterpret_cast<float4*>(kvp +  0) = make_float4(kk[0],kk[1],kk[2],kk[3]);
            *reinterpret_cast<float4*>(kvp +  4) = make_float4(kk[4],kk[5],kk[6],kk[7]);
            *reinterpret_cast<float4*>(kvp +  8) = make_float4(vv[0],vv[1],vv[2],vv[3]);
            *reinterpret_cast<float4*>(kvp + 12) = make_float4(vv[4],vv[5],vv[6],vv[7]);
        };
        if (active) { qkv(x0, t0, q0); qkv(x1, t0 + 1, q1); }

        __syncthreads();   // K/V visible

        if (active) {
            // ---- one-pass softmax attention, 2 tokens x 2 heads ----
            float l00=0.f,l01=0.f,l10=0.f,l11=0.f;
            float a00x=0.f,a00y=0.f,a00z=0.f,a00w=0.f;
            float a01x=0.f,a01y=0.f,a01z=0.f,a01w=0.f;
            float a10x=0.f,a10y=0.f,a10z=0.f,a10w=0.f;
            float a11x=0.f,a11y=0.f,a11z=0.f,a11w=0.f;
            const float* kvb = kv + imgl * KV_STRIDE;
            #pragma unroll 2
            for (int s = 0; s < T_TOK; ++s) {
                const float* sp = kvb + s * 16;
                float4 k0 = *reinterpret_cast<const float4*>(sp);
                float4 k1 = *reinterpret_cast<const float4*>(sp + 4);
                float4 v0 = *reinterpret_cast<const float4*>(sp + 8);
                float4 v1 = *reinterpret_cast<const float4*>(sp + 12);
                float d, p;
                d = q0[0]*k0.x + q0[1]*k0.y + q0[2]*k0.z + q0[3]*k0.w;
                p = __expf(d);
                l00 += p; a00x += p*v0.x; a00y += p*v0.y; a00z += p*v0.z; a00w += p*v0.w;
                d = q0[4]*k1.x + q0[5]*k1.y + q0[6]*k1.z + q0[7]*k1.w;
                p = __expf(d);
                l01 += p; a01x += p*v1.x; a01y += p*v1.y; a01z += p*v1.z; a01w += p*v1.w;
                d = q1[0]*k0.x + q1[1]*k0.y + q1[2]*k0.z + q1[3]*k0.w;
                p = __expf(d);
                l10 += p; a10x += p*v0.x; a10y += p*v0.y; a10z += p*v0.z; a10w += p*v0.w;
                d = q1[4]*k1.x + q1[5]*k1.y + q1[6]*k1.z + q1[7]*k1.w;
                p = __expf(d);
                l11 += p; a11x += p*v1.x; a11y += p*v1.y; a11z += p*v1.z; a11w += p*v1.w;
            }
            float o0[8], o1[8], r;
            r = 1.f/l00; o0[0]=a00x*r; o0[1]=a00y*r; o0[2]=a00z*r; o0[3]=a00w*r;
            r = 1.f/l01; o0[4]=a01x*r; o0[5]=a01y*r; o0[6]=a01z*r; o0[7]=a01w*r;
            r = 1.f/l10; o1[0]=a10x*r; o1[1]=a10y*r; o1[2]=a10z*r; o1[3]=a10w*r;
            r = 1.f/l11; o1[4]=a11x*r; o1[5]=a11y*r; o1[6]=a11z*r; o1[7]=a11w*r;

            // ---- proj + residual + LN2 + FF, per token ----
            auto tail = [&](float* x, const float* o) {
                float xn[8];
                #pragma unroll
                for (int e = 0; e < 8; ++e) {
                    float a = Pb[w8 + e];
                    #pragma unroll
                    for (int d = 0; d < 8; ++d) a += o[d] * Pw[w64 + e*8 + d];
                    xn[e] = x[e] + a;
                }
                float mu = 0.f;
                #pragma unroll
                for (int d = 0; d < 8; ++d) mu += xn[d];
                mu *= 0.125f;
                float var = 0.f;
                #pragma unroll
                for (int d = 0; d < 8; ++d) { float dd = xn[d] - mu; var += dd * dd; }
                var *= 0.125f;
                const float rs2 = rsqrtf(var + 1e-5f);
                float h2[8];
                #pragma unroll
                for (int d = 0; d < 8; ++d)
                    h2[d] = (xn[d] - mu) * rs2 * g2[w8 + d] + be2[w8 + d];
                float acc[8] = {0.f,0.f,0.f,0.f,0.f,0.f,0.f,0.f};
                #pragma unroll 4
                for (int f = 0; f < 32; ++f) {
                    float a = bb1[w32 + f];
                    #pragma unroll
                    for (int d = 0; d < 8; ++d) a += h2[d] * W1[w256 + f*8 + d];
                    a = fmaxf(a, 0.f);
                    #pragma unroll
                    for (int d = 0; d < 8; ++d) acc[d] += a * W2[w256 + d*32 + f];
                }
                #pragma unroll
                for (int d = 0; d < 8; ++d) x[d] = xn[d] + acc[d] + bb2[w8 + d];
            };
            tail(x0, o0);
            tail(x1, o1);
        }
    }

    // ---- classification head: lanes holding token 0 ----
    if (active && lt == 0) {
        float lg[10]; float mx = -1e30f;
        #pragma unroll
        for (int c = 0; c < 10; ++c) {
            float a = mlpb[c];
            #pragma unroll
            for (int d = 0; d < 8; ++d) a += x0[d] * mlpW[c*8 + d];
            lg[c] = a; mx = fmaxf(mx, a);
        }
        float ssum = 0.f;
        #pragma unroll
        for (int c = 0; c < 10; ++c) { lg[c] = __expf(lg[c] - mx); ssum += lg[c]; }
        const float rsum = 1.f / ssum;
        #pragma unroll
        for (int c = 0; c < 10; ++c)
            out[(size_t)gimg*10 + c] = lg[c] * rsum;
    }
}

extern "C" void kernel_launch(void* const* d_in, const int* in_sizes, int n_in,
                              void* d_out, int out_size, void* d_ws, size_t ws_size,
                              hipStream_t stream) {
    const int B = in_sizes[0] / 784;
    const int nblk = (B + IMGS_PB - 1) / IMGS_PB;
    vit_fwd<<<nblk, THREADS, 0, stream>>>(
        (const float*)d_in[0],  (const float*)d_in[1],  (const float*)d_in[2],
        (const float*)d_in[3],  (const float*)d_in[4],  (const float*)d_in[5],
        (const float*)d_in[6],  (const float*)d_in[7],  (const float*)d_in[8],
        (const float*)d_in[9],  (const float*)d_in[10], (const float*)d_in[11],
        (const float*)d_in[12], (const float*)d_in[13], (const float*)d_in[14],
        (const float*)d_in[15], (const float*)d_in[16], (const float*)d_in[17],
        (float*)d_out, B);
}